// Round 8
// baseline (122.528 us; speedup 1.0000x reference)
//
#include <hip/hip_runtime.h>

#define IN_DIM   320
#define POOL_DIM 256
#define HID      128
#define RPB      128            // rows per block (4 waves x 32 rows)
#define NKC      10             // 320 / 32
#define NSEG     16             // max graph segments per 128-row block

typedef __attribute__((ext_vector_type(8))) short bf16x8;
typedef __attribute__((ext_vector_type(4))) float f32x4;

typedef __attribute__((address_space(1))) const unsigned int guint;
typedef __attribute__((address_space(3))) unsigned int luint;

__device__ __forceinline__ void gl_lds16(const void* g, void* l) {
    __builtin_amdgcn_global_load_lds((guint*)g, (luint*)l, 16, 0, 0);
}

__device__ __forceinline__ unsigned fbits(float f) {
    union { float f; unsigned u; } c; c.f = f; return c.u;
}
// pack bf16(trunc) of two f32 bit patterns: low16 = u0>>16, high16 = u1>>16
__device__ __forceinline__ unsigned pack2(unsigned u0, unsigned u1) {
    return __builtin_amdgcn_perm(u1, u0, 0x07060302u);
}

// split 8 f32 into hi(trunc-bf16) + lo(bf16 of residual); hi+lo ~ f32 exact
// to ~2^-16 relative.
__device__ __forceinline__ void split8(float4 a, float4 b, bf16x8& hi, bf16x8& lo) {
    float f[8] = { a.x, a.y, a.z, a.w, b.x, b.y, b.z, b.w };
    unsigned hu[8], lu[8];
#pragma unroll
    for (int i = 0; i < 8; ++i) {
        unsigned u = fbits(f[i]);
        hu[i] = u;
        float hif = __builtin_bit_cast(float, u & 0xffff0000u);
        lu[i] = fbits(f[i] - hif);
    }
    int4 hp, lp;
    hp.x = pack2(hu[0], hu[1]); hp.y = pack2(hu[2], hu[3]);
    hp.z = pack2(hu[4], hu[5]); hp.w = pack2(hu[6], hu[7]);
    lp.x = pack2(lu[0], lu[1]); lp.y = pack2(lu[2], lu[3]);
    lp.z = pack2(lu[4], lu[5]); lp.w = pack2(lu[6], lu[7]);
    hi = __builtin_bit_cast(bf16x8, hp);
    lo = __builtin_bit_cast(bf16x8, lp);
}

// ---------------------------------------------------------------------------
// One-time: pack W1 into MFMA B-fragment order, split hi/lo (frag-linear):
//   Wpk[((kc*16 + ht*2 + s)*64 + lane)*8 + j] =
//       split_s( W1[h = ht*16 + (lane&15)][k = kc*32 + (lane>>4)*8 + j] )
// ---------------------------------------------------------------------------
__global__ __launch_bounds__(256) void pack_w1_kernel(
    const float* __restrict__ W1, ushort* __restrict__ Wpk)
{
    const int i = blockIdx.x * 256 + threadIdx.x;   // one bf16x8 group each
    if (i >= NKC * 8 * 2 * 64) return;
    const int kc   = i >> 10;
    const int r    = i & 1023;
    const int ht   = r >> 7;
    const int r2   = r & 127;
    const int s    = r2 >> 6;
    const int lane = r2 & 63;
    const int h    = ht * 16 + (lane & 15);
    const int k0   = kc * 32 + (lane >> 4) * 8;

    ushort v[8];
#pragma unroll
    for (int j = 0; j < 8; ++j) {
        const float f = W1[(size_t)h * IN_DIM + k0 + j];
        const unsigned u = fbits(f);
        if (s == 0) {
            v[j] = (ushort)(u >> 16);
        } else {
            const float hif = __builtin_bit_cast(float, u & 0xffff0000u);
            v[j] = (ushort)(fbits(f - hif) >> 16);
        }
    }
    ushort* dst = Wpk + (size_t)i * 8;
#pragma unroll
    for (int j = 0; j < 8; ++j) dst[j] = v[j];
}

// ---------------------------------------------------------------------------
// Kernel A (fused): scores via split-bf16 MFMA (W double-buffered in LDS via
// global_load_lds), then per-(block,segment) partial weighted sums
//   P[b][s][rg][col4] = sum_{rows of segment, row%4==rg} exp(s_i - m_b) * z_i
// using the z rows still hot in L2. Segments of sorted batch_index found by
// per-wave __ballot boundary scan. meta[b][s] = graph id (-1 unused).
// ---------------------------------------------------------------------------
__global__ __launch_bounds__(256) void attn_fused(
    const float* __restrict__ z, const ushort* __restrict__ Wpk,
    const float* __restrict__ b1, const float* __restrict__ W2,
    const float* __restrict__ b2, const int* __restrict__ bidx,
    float* __restrict__ bmax, float* __restrict__ bsum,
    float* __restrict__ P, int* __restrict__ meta, int N)
{
    __shared__ float4 wbuf[2][1024];   // 2 x 16 KB W-fragment buffers
    __shared__ float  sblk[RPB];
    __shared__ int    gbid[RPB];
    __shared__ int    seg_s0[RPB + 1];
    __shared__ int    seg_gid[RPB];
    __shared__ int    scnt[2];
    __shared__ float  mshare;

    const int tid  = threadIdx.x;
    const int wid  = tid >> 6;
    const int lane = tid & 63;
    const int lm   = lane & 15;
    const int lg   = lane >> 4;
    const int r0   = blockIdx.x * RPB;
    const int wr0  = r0 + wid * 32;
    const int nvalid = (N - r0 < RPB) ? (N - r0) : RPB;

    int row0 = wr0 + lm;      if (row0 > N - 1) row0 = N - 1;
    int row1 = wr0 + 16 + lm; if (row1 > N - 1) row1 = N - 1;
    const float* zp0 = z + (size_t)row0 * IN_DIM + lg * 8;
    const float* zp1 = z + (size_t)row1 * IN_DIM + lg * 8;

    #define STAGE_W(kc_, b_)                                                  \
        { const char* src = (const char*)Wpk + (size_t)(kc_) * 16384;         \
          char* dst = (char*)&wbuf[b_][0];                                    \
          _Pragma("unroll")                                                   \
          for (int j = 0; j < 4; ++j) {                                       \
              const int o = (tid + j * 256) * 16;                             \
              gl_lds16(src + o, dst + o);                                     \
          } }

    f32x4 acc[2][8];
#pragma unroll
    for (int rt = 0; rt < 2; ++rt)
#pragma unroll
        for (int ht = 0; ht < 8; ++ht) acc[rt][ht] = (f32x4){0.f, 0.f, 0.f, 0.f};

    float4 zraw[2][4];
    bf16x8 af[2][4];   // [buf][a0h,a0l,a1h,a1l]

    STAGE_W(0, 0);

    {   // prologue: load z[0], z[1]; split z[0]
        const float4* p0 = (const float4*)zp0;
        const float4* p1 = (const float4*)zp1;
        zraw[0][0] = p0[0]; zraw[0][1] = p0[1];
        zraw[0][2] = p1[0]; zraw[0][3] = p1[1];
        const float4* q0 = (const float4*)(zp0 + 32);
        const float4* q1 = (const float4*)(zp1 + 32);
        zraw[1][0] = q0[0]; zraw[1][1] = q0[1];
        zraw[1][2] = q1[0]; zraw[1][3] = q1[1];
        split8(zraw[0][0], zraw[0][1], af[0][0], af[0][1]);
        split8(zraw[0][2], zraw[0][3], af[0][2], af[0][3]);
    }
    __syncthreads();   // W[0] staged

#pragma unroll
    for (int kc = 0; kc < NKC; ++kc) {
        const int cb  = kc & 1;
        const int nb2 = cb ^ 1;

        if (kc + 1 < NKC) STAGE_W(kc + 1, nb2);

        const char* wb_base = (const char*)&wbuf[cb][0] + lane * 16;
#pragma unroll
        for (int ht = 0; ht < 8; ++ht) {
            const bf16x8 bh = *(const bf16x8*)(wb_base + ht * 2048);
            const bf16x8 bl = *(const bf16x8*)(wb_base + ht * 2048 + 1024);
            acc[0][ht] = __builtin_amdgcn_mfma_f32_16x16x32_bf16(af[cb][0], bh, acc[0][ht], 0, 0, 0);
            acc[0][ht] = __builtin_amdgcn_mfma_f32_16x16x32_bf16(af[cb][1], bh, acc[0][ht], 0, 0, 0);
            acc[0][ht] = __builtin_amdgcn_mfma_f32_16x16x32_bf16(af[cb][0], bl, acc[0][ht], 0, 0, 0);
            acc[1][ht] = __builtin_amdgcn_mfma_f32_16x16x32_bf16(af[cb][2], bh, acc[1][ht], 0, 0, 0);
            acc[1][ht] = __builtin_amdgcn_mfma_f32_16x16x32_bf16(af[cb][3], bh, acc[1][ht], 0, 0, 0);
            acc[1][ht] = __builtin_amdgcn_mfma_f32_16x16x32_bf16(af[cb][2], bl, acc[1][ht], 0, 0, 0);
        }

        if (kc + 2 < NKC) {
            const int ko2 = (kc + 2) * 32;
            const float4* p0 = (const float4*)(zp0 + ko2);
            const float4* p1 = (const float4*)(zp1 + ko2);
            zraw[cb][0] = p0[0]; zraw[cb][1] = p0[1];
            zraw[cb][2] = p1[0]; zraw[cb][3] = p1[1];
        }

        if (kc + 1 < NKC) {
            split8(zraw[nb2][0], zraw[nb2][1], af[nb2][0], af[nb2][1]);
            split8(zraw[nb2][2], zraw[nb2][3], af[nb2][2], af[nb2][3]);
            __syncthreads();   // W[kc+1] staged; buf readers done
        }
    }

    // ---- score epilogue: relu + dot(W2), reduce over 16 cols -> sblk
    float b1v[8], w2v[8];
#pragma unroll
    for (int ht = 0; ht < 8; ++ht) {
        b1v[ht] = b1[ht * 16 + lm];
        w2v[ht] = W2[ht * 16 + lm];
    }
    const float b2v = b2[0];

#pragma unroll
    for (int rt = 0; rt < 2; ++rt) {
#pragma unroll
        for (int reg = 0; reg < 4; ++reg) {
            float s = 0.f;
#pragma unroll
            for (int ht = 0; ht < 8; ++ht)
                s += fmaxf(acc[rt][ht][reg] + b1v[ht], 0.f) * w2v[ht];
            s += __shfl_xor(s, 1);
            s += __shfl_xor(s, 2);
            s += __shfl_xor(s, 4);
            s += __shfl_xor(s, 8);
            s += b2v;
            if (lm == 0) {
                const int rloc = wid * 32 + rt * 16 + lg * 4 + reg;
                sblk[rloc] = (rloc < nvalid) ? s : -1e30f;
            }
        }
    }
    __syncthreads();

    // ---- block (max, sum-exp) + stage batch ids
    if (tid < 64) {
        const float v0 = sblk[tid];
        const float v1 = sblk[tid + 64];
        float m = fmaxf(v0, v1);
#pragma unroll
        for (int d = 1; d < 64; d <<= 1) m = fmaxf(m, __shfl_xor(m, d, 64));
        float e = __expf(v0 - m) + __expf(v1 - m);
#pragma unroll
        for (int d = 1; d < 64; d <<= 1) e += __shfl_xor(e, d, 64);
        if (tid == 0) {
            bmax[blockIdx.x] = m;
            bsum[blockIdx.x] = e;
            mshare = m;
        }
    }
    if (tid >= 128 && tid < 256) {
        const int row = tid - 128;
        gbid[row] = (row < nvalid) ? bidx[r0 + row] : -2;
    }
    __syncthreads();

    // ---- segment scan: per-wave ballot over boundary flags (rows 0..127)
    int flag = 0, idx = 0;
    if (tid < 128) {
        const int prev = (tid == 0) ? -999999 : gbid[tid - 1];
        flag = (gbid[tid] != prev) ? 1 : 0;
        const unsigned long long mask = __ballot(flag);
        idx = __popcll(mask & ((1ull << (tid & 63)) - 1ull));
        if ((tid & 63) == 0) scnt[tid >> 6] = (int)__popcll(mask);
    }
    __syncthreads();
    const int nseg = scnt[0] + scnt[1];
    if (tid < 128 && flag) {
        const int pos = idx + ((tid >= 64) ? scnt[0] : 0);
        seg_s0[pos]  = tid;
        seg_gid[pos] = gbid[tid];
    }
    if (tid == 0) seg_s0[nseg] = RPB;
    __syncthreads();

    // ---- per-segment weighted partial sums (z rows hot in L2)
    const int rg    = tid >> 6;     // row-group 0..3
    const float mb  = mshare;
    const f32x4* zf = (const f32x4*)z;   // 80 f32x4 per row; use first 64
    f32x4* P4 = (f32x4*)P;

    for (int s = 0; s < nseg && s < NSEG; ++s) {
        const int gid = seg_gid[s];
        if (gid < 0) continue;      // invalid tail marker
        const int rs = seg_s0[s];
        const int re = seg_s0[s + 1];
        f32x4 a = (f32x4){0.f, 0.f, 0.f, 0.f};
        for (int row = rs + rg; row < re; row += 4) {
            const float w = __expf(sblk[row] - mb);
            a += w * zf[(size_t)(r0 + row) * 80 + lane];
        }
        P4[(((size_t)blockIdx.x * NSEG + s) * 4 + rg) * 64 + lane] = a;
    }
    if (tid < NSEG)
        meta[blockIdx.x * NSEG + tid] =
            (tid < nseg && tid < NSEG) ? seg_gid[tid] : -1;
}

// ---------------------------------------------------------------------------
// Kernel B: combine per-block (max, sumexp) -> global max & softmax denom
// ---------------------------------------------------------------------------
__global__ __launch_bounds__(256) void softmax_reduce_kernel(
    const float* __restrict__ bmax, const float* __restrict__ bsum,
    float* __restrict__ red, int nb)
{
    __shared__ float sm[4];
    __shared__ float ss[4];
    const int tid = threadIdx.x;

    float m = -1e30f;
    for (int i = tid; i < nb; i += 256) m = fmaxf(m, bmax[i]);
#pragma unroll
    for (int d = 1; d < 64; d <<= 1) m = fmaxf(m, __shfl_xor(m, d, 64));
    if ((tid & 63) == 0) sm[tid >> 6] = m;
    __syncthreads();
    const float gmax = fmaxf(fmaxf(sm[0], sm[1]), fmaxf(sm[2], sm[3]));

    float s = 0.f;
    for (int i = tid; i < nb; i += 256) s += bsum[i] * __expf(bmax[i] - gmax);
#pragma unroll
    for (int d = 1; d < 64; d <<= 1) s += __shfl_xor(s, d, 64);
    if ((tid & 63) == 0) ss[tid >> 6] = s;
    __syncthreads();
    if (tid == 0) {
        red[0] = gmax;
        red[1] = ss[0] + ss[1] + ss[2] + ss[3];
    }
}

// ---------------------------------------------------------------------------
// Kernel C: per-graph combine of block partials.
// out[g] = (1/den/count) * sum_{b overlapping g} exp(m_b - gmax) * P_b[g]
// ---------------------------------------------------------------------------
__device__ __forceinline__ int lower_bound(const int* __restrict__ a, int n, int key)
{
    int lo = 0, hi = n;
    while (lo < hi) {
        int mid = (lo + hi) >> 1;
        if (a[mid] < key) lo = mid + 1; else hi = mid;
    }
    return lo;
}

__global__ __launch_bounds__(64) void combine_kernel(
    const int* __restrict__ bidx, const float* __restrict__ bmax,
    const float* __restrict__ red, const float* __restrict__ P,
    const int* __restrict__ meta, float* __restrict__ out, int N)
{
    const int g    = blockIdx.x;
    const int lane = threadIdx.x;

    const int start = lower_bound(bidx, N, g);
    const int end   = lower_bound(bidx, N, g + 1);
    const float gmax    = red[0];
    const float inv_den = 1.0f / red[1];

    f32x4 a = (f32x4){0.f, 0.f, 0.f, 0.f};
    if (end > start) {
        const int b0 = start >> 7;
        const int b1 = (end - 1) >> 7;
        const f32x4* P4 = (const f32x4*)P;
        for (int b = b0; b <= b1; ++b) {
            int s = -1;
#pragma unroll
            for (int k = 0; k < NSEG; ++k)
                if (meta[b * NSEG + k] == g) s = k;
            if (s < 0) continue;
            const size_t base = (((size_t)b * NSEG + s) * 4) * 64 + lane;
            const f32x4 t = (P4[base] + P4[base + 64]) +
                            (P4[base + 128] + P4[base + 192]);
            a += __expf(bmax[b] - gmax) * t;
        }
    }
    const int cnt = end - start;
    const float sc = inv_den / fmaxf((float)cnt, 1.0f);
    ((f32x4*)out)[(size_t)g * 64 + lane] = a * sc;
}

// ---------------------------------------------------------------------------
extern "C" void kernel_launch(void* const* d_in, const int* in_sizes, int n_in,
                              void* d_out, int out_size, void* d_ws, size_t ws_size,
                              hipStream_t stream)
{
    const float* z    = (const float*)d_in[0];
    const int*   bidx = (const int*)  d_in[1];
    const float* W1   = (const float*)d_in[2];
    const float* b1   = (const float*)d_in[3];
    const float* W2   = (const float*)d_in[4];
    const float* b2   = (const float*)d_in[5];
    float*       out  = (float*)d_out;

    const int N  = in_sizes[0] / IN_DIM;       // 200000
    const int G  = out_size / POOL_DIM;        // 2000
    const int nb = (N + RPB - 1) / RPB;        // 1563 (<= 1600 padded)

    // workspace layout (1600-block padding; ws_size ~1 GB per round-7 fill)
    float*  bmax = (float*)d_ws;                       // 1600
    float*  bsum = bmax + 1600;                        // 1600
    float*  red  = bsum + 1600;                        // 16
    int*    meta = (int*)(red + 16);                   // 1600*NSEG ints
    float*  P    = (float*)(meta + 1600 * NSEG);       // 1600*NSEG*4*256 floats
    ushort* Wpk  = (ushort*)(P + (size_t)1600 * NSEG * 4 * 256);  // 160 KB

    pack_w1_kernel<<<(NKC * 8 * 2 * 64 + 255) / 256, 256, 0, stream>>>(W1, Wpk);
    attn_fused<<<nb, 256, 0, stream>>>(z, Wpk, b1, W2, b2, bidx,
                                       bmax, bsum, P, meta, N);
    softmax_reduce_kernel<<<1, 256, 0, stream>>>(bmax, bsum, red, nb);
    combine_kernel<<<G, 64, 0, stream>>>(bidx, bmax, red, P, meta, out, N);
}

// Round 9
// 116.791 us; speedup vs baseline: 1.0491x; 1.0491x over previous
//
#include <hip/hip_runtime.h>

#define IN_DIM   320
#define POOL_DIM 256
#define HID      128
#define RPB      128            // rows per block (4 waves x 32 rows)
#define NKC      10             // 320 / 32

typedef __attribute__((ext_vector_type(8))) short bf16x8;
typedef __attribute__((ext_vector_type(4))) float f32x4;

typedef __attribute__((address_space(1))) const unsigned int guint;
typedef __attribute__((address_space(3))) unsigned int luint;

__device__ __forceinline__ void gl_lds16(const void* g, void* l) {
    __builtin_amdgcn_global_load_lds((guint*)g, (luint*)l, 16, 0, 0);
}

__device__ __forceinline__ unsigned fbits(float f) {
    union { float f; unsigned u; } c; c.f = f; return c.u;
}
// pack bf16(trunc) of two f32 bit patterns: low16 = u0>>16, high16 = u1>>16
__device__ __forceinline__ unsigned pack2(unsigned u0, unsigned u1) {
    return __builtin_amdgcn_perm(u1, u0, 0x07060302u);
}

// split 8 f32 into hi(trunc-bf16) + lo(bf16 of residual); hi+lo ~ f32 exact
// to ~2^-16 relative.
__device__ __forceinline__ void split8(float4 a, float4 b, bf16x8& hi, bf16x8& lo) {
    float f[8] = { a.x, a.y, a.z, a.w, b.x, b.y, b.z, b.w };
    unsigned hu[8], lu[8];
#pragma unroll
    for (int i = 0; i < 8; ++i) {
        unsigned u = fbits(f[i]);
        hu[i] = u;
        float hif = __builtin_bit_cast(float, u & 0xffff0000u);
        lu[i] = fbits(f[i] - hif);
    }
    int4 hp, lp;
    hp.x = pack2(hu[0], hu[1]); hp.y = pack2(hu[2], hu[3]);
    hp.z = pack2(hu[4], hu[5]); hp.w = pack2(hu[6], hu[7]);
    lp.x = pack2(lu[0], lu[1]); lp.y = pack2(lu[2], lu[3]);
    lp.z = pack2(lu[4], lu[5]); lp.w = pack2(lu[6], lu[7]);
    hi = __builtin_bit_cast(bf16x8, hp);
    lo = __builtin_bit_cast(bf16x8, lp);
}

// ---------------------------------------------------------------------------
// One-time: pack W1 into MFMA B-fragment order, split hi/lo (frag-linear):
//   Wpk[((kc*16 + ht*2 + s)*64 + lane)*8 + j] =
//       split_s( W1[h = ht*16 + (lane&15)][k = kc*32 + (lane>>4)*8 + j] )
// Frag-linear => the 16KB per-kc chunk can be DMA'd to LDS verbatim.
// ---------------------------------------------------------------------------
__global__ __launch_bounds__(256) void pack_w1_kernel(
    const float* __restrict__ W1, ushort* __restrict__ Wpk)
{
    const int i = blockIdx.x * 256 + threadIdx.x;   // one bf16x8 group each
    if (i >= NKC * 8 * 2 * 64) return;
    const int kc   = i >> 10;
    const int r    = i & 1023;
    const int ht   = r >> 7;
    const int r2   = r & 127;
    const int s    = r2 >> 6;
    const int lane = r2 & 63;
    const int h    = ht * 16 + (lane & 15);
    const int k0   = kc * 32 + (lane >> 4) * 8;

    ushort v[8];
#pragma unroll
    for (int j = 0; j < 8; ++j) {
        const float f = W1[(size_t)h * IN_DIM + k0 + j];
        const unsigned u = fbits(f);
        if (s == 0) {
            v[j] = (ushort)(u >> 16);
        } else {
            const float hif = __builtin_bit_cast(float, u & 0xffff0000u);
            v[j] = (ushort)(fbits(f - hif) >> 16);
        }
    }
    ushort* dst = Wpk + (size_t)i * 8;
#pragma unroll
    for (int j = 0; j < 8; ++j) dst[j] = v[j];
}

// ---------------------------------------------------------------------------
// Kernel A: scores via split-bf16 MFMA.  BOTH streams (W frags and z chunk)
// double-buffered in LDS via global_load_lds (fire-and-forget DMA).
// z LDS layout: slot s = row*8 + (q ^ (row&7)), 16B/slot, LINEAR dest
// (DMA writes base+lane*16); the XOR swizzle is applied to the per-lane
// GLOBAL source quad. Read side: per 8-lane group slot%8 = (2lg+c)^(lm&7)
// covers all 8 values -> conflict-free ds_read_b128.
// One vmcnt(0)+barrier per kc (implicit in __syncthreads) covers both DMAs.
// mfma_f32_16x16x32_bf16: A row=l&15, k=(l>>4)*8+j; C/D col=l&15,
// row=(l>>4)*4+reg.  3-term split product (drop lo*lo ~ 2^-16 rel).
// ---------------------------------------------------------------------------
__global__ __launch_bounds__(256) void attn_scores_mfma(
    const float* __restrict__ z, const ushort* __restrict__ Wpk,
    const float* __restrict__ b1, const float* __restrict__ W2,
    const float* __restrict__ b2,
    float* __restrict__ scores, float* __restrict__ bmax,
    float* __restrict__ bsum, int N)
{
    __shared__ float4 wbuf[2][1024];   // 2 x 16 KB W-fragment buffers
    __shared__ float4 zbuf[2][1024];   // 2 x 16 KB z chunk buffers
    __shared__ float  sblk[RPB];

    const int tid  = threadIdx.x;
    const int wid  = tid >> 6;
    const int lane = tid & 63;
    const int lm   = lane & 15;
    const int lg   = lane >> 4;
    const int r0   = blockIdx.x * RPB;

    // per-thread z DMA source bases (4 slots, swizzled quad, row-clamped)
    const char* zsrc[4];
#pragma unroll
    for (int j = 0; j < 4; ++j) {
        const int s   = tid + j * 256;
        const int row = s >> 3;
        const int q   = (s & 7) ^ (row & 7);
        int gr = r0 + row; if (gr > N - 1) gr = N - 1;
        zsrc[j] = (const char*)z + (size_t)gr * (IN_DIM * 4) + q * 16;
    }

    #define STAGE_W(kc_, b_)                                                  \
        { const char* src = (const char*)Wpk + (size_t)(kc_) * 16384;         \
          char* dst = (char*)&wbuf[b_][0];                                    \
          _Pragma("unroll")                                                   \
          for (int j = 0; j < 4; ++j) {                                       \
              const int o = (tid + j * 256) * 16;                             \
              gl_lds16(src + o, dst + o);                                     \
          } }

    #define STAGE_Z(kc_, b_)                                                  \
        { char* dst = (char*)&zbuf[b_][0];                                    \
          _Pragma("unroll")                                                   \
          for (int j = 0; j < 4; ++j) {                                       \
              const int o = (tid + j * 256) * 16;                             \
              gl_lds16(zsrc[j] + (kc_) * 128, dst + o);                       \
          } }

    f32x4 acc[2][8];
#pragma unroll
    for (int rt = 0; rt < 2; ++rt)
#pragma unroll
        for (int ht = 0; ht < 8; ++ht) acc[rt][ht] = (f32x4){0.f, 0.f, 0.f, 0.f};

    // reader addresses (loop-invariant): two rows, two swizzled quads each
    const int lr0 = wid * 32 + lm;
    const int lr1 = lr0 + 16;
    const int i00 = lr0 * 8 + ((2 * lg)     ^ (lr0 & 7));
    const int i01 = lr0 * 8 + ((2 * lg + 1) ^ (lr0 & 7));
    const int i10 = lr1 * 8 + ((2 * lg)     ^ (lr1 & 7));
    const int i11 = lr1 * 8 + ((2 * lg + 1) ^ (lr1 & 7));

    STAGE_Z(0, 0);
    STAGE_W(0, 0);
    __syncthreads();   // implicit vmcnt(0): both DMAs landed

#pragma unroll
    for (int kc = 0; kc < NKC; ++kc) {
        const int cb  = kc & 1;          // constant after unroll
        const int nb2 = cb ^ 1;

        // issue next-chunk DMAs first (they write buf^1; its readers
        // finished before the barrier that ended iter kc-1)
        if (kc + 1 < NKC) {
            STAGE_Z(kc + 1, nb2);
            STAGE_W(kc + 1, nb2);
        }

        // z frags from LDS -> split8
        bf16x8 a0h, a0l, a1h, a1l;
        {
            const float4* zb = &zbuf[cb][0];
            const float4 x0 = zb[i00];
            const float4 x1 = zb[i01];
            const float4 y0 = zb[i10];
            const float4 y1 = zb[i11];
            split8(x0, x1, a0h, a0l);
            split8(y0, y1, a1h, a1l);
        }

        // W frags + MFMAs
        const char* wb_base = (const char*)&wbuf[cb][0] + lane * 16;
#pragma unroll
        for (int ht = 0; ht < 8; ++ht) {
            const bf16x8 bh = *(const bf16x8*)(wb_base + ht * 2048);
            const bf16x8 bl = *(const bf16x8*)(wb_base + ht * 2048 + 1024);
            acc[0][ht] = __builtin_amdgcn_mfma_f32_16x16x32_bf16(a0h, bh, acc[0][ht], 0, 0, 0);
            acc[0][ht] = __builtin_amdgcn_mfma_f32_16x16x32_bf16(a0l, bh, acc[0][ht], 0, 0, 0);
            acc[0][ht] = __builtin_amdgcn_mfma_f32_16x16x32_bf16(a0h, bl, acc[0][ht], 0, 0, 0);
            acc[1][ht] = __builtin_amdgcn_mfma_f32_16x16x32_bf16(a1h, bh, acc[1][ht], 0, 0, 0);
            acc[1][ht] = __builtin_amdgcn_mfma_f32_16x16x32_bf16(a1l, bh, acc[1][ht], 0, 0, 0);
            acc[1][ht] = __builtin_amdgcn_mfma_f32_16x16x32_bf16(a1h, bl, acc[1][ht], 0, 0, 0);
        }

        if (kc + 1 < NKC) __syncthreads();  // next DMAs landed; readers done
    }

    // ---- epilogue: relu + dot(W2) per lane-col, reduce over 16 cols
    float b1v[8], w2v[8];
#pragma unroll
    for (int ht = 0; ht < 8; ++ht) {
        b1v[ht] = b1[ht * 16 + lm];
        w2v[ht] = W2[ht * 16 + lm];
    }
    const float b2v = b2[0];

#pragma unroll
    for (int rt = 0; rt < 2; ++rt) {
#pragma unroll
        for (int reg = 0; reg < 4; ++reg) {
            float s = 0.f;
#pragma unroll
            for (int ht = 0; ht < 8; ++ht)
                s += fmaxf(acc[rt][ht][reg] + b1v[ht], 0.f) * w2v[ht];
            s += __shfl_xor(s, 1);
            s += __shfl_xor(s, 2);
            s += __shfl_xor(s, 4);
            s += __shfl_xor(s, 8);
            s += b2v;
            if (lm == 0) {
                const int rloc = wid * 32 + rt * 16 + lg * 4 + reg;
                const int grow = r0 + rloc;
                if (grow < N) {
                    scores[grow] = s;
                    sblk[rloc] = s;
                } else {
                    sblk[rloc] = -1e30f;
                }
            }
        }
    }
    __syncthreads();

    // ---- block (max, sum-exp): 128 scores folded into one wave
    if (tid < 64) {
        const float v0 = sblk[tid];
        const float v1 = sblk[tid + 64];
        float m = fmaxf(v0, v1);
#pragma unroll
        for (int d = 1; d < 64; d <<= 1) m = fmaxf(m, __shfl_xor(m, d, 64));
        float e = __expf(v0 - m) + __expf(v1 - m);
#pragma unroll
        for (int d = 1; d < 64; d <<= 1) e += __shfl_xor(e, d, 64);
        if (tid == 0) {
            bmax[blockIdx.x] = m;
            bsum[blockIdx.x] = e;
        }
    }
}

// ---------------------------------------------------------------------------
// Kernel B: combine per-block (max, sumexp) -> global max & softmax denom
// ---------------------------------------------------------------------------
__global__ __launch_bounds__(256) void softmax_reduce_kernel(
    const float* __restrict__ bmax, const float* __restrict__ bsum,
    float* __restrict__ red, int nb)
{
    __shared__ float sm[4];
    __shared__ float ss[4];
    const int tid = threadIdx.x;

    float m = -1e30f;
    for (int i = tid; i < nb; i += 256) m = fmaxf(m, bmax[i]);
#pragma unroll
    for (int d = 1; d < 64; d <<= 1) m = fmaxf(m, __shfl_xor(m, d, 64));
    if ((tid & 63) == 0) sm[tid >> 6] = m;
    __syncthreads();
    const float gmax = fmaxf(fmaxf(sm[0], sm[1]), fmaxf(sm[2], sm[3]));

    float s = 0.f;
    for (int i = tid; i < nb; i += 256) s += bsum[i] * __expf(bmax[i] - gmax);
#pragma unroll
    for (int d = 1; d < 64; d <<= 1) s += __shfl_xor(s, d, 64);
    if ((tid & 63) == 0) ss[tid >> 6] = s;
    __syncthreads();
    if (tid == 0) {
        red[0] = gmax;
        red[1] = ss[0] + ss[1] + ss[2] + ss[3];
    }
}

// ---------------------------------------------------------------------------
// Kernel E: per-graph weighted mean, float4-vectorized.
// Block = 256 threads = 4 row-groups x 64 float4-lanes (256 cols).
// ---------------------------------------------------------------------------
__device__ __forceinline__ int lower_bound(const int* __restrict__ a, int n, int key)
{
    int lo = 0, hi = n;
    while (lo < hi) {
        int mid = (lo + hi) >> 1;
        if (a[mid] < key) lo = mid + 1; else hi = mid;
    }
    return lo;
}

__global__ __launch_bounds__(256) void pool_kernel(
    const float* __restrict__ z, const int* __restrict__ bidx,
    const float* __restrict__ scores, const float* __restrict__ red,
    float* __restrict__ out, int N)
{
    const int g    = blockIdx.x;
    const int lane = threadIdx.x & 63;   // float4 column
    const int rg   = threadIdx.x >> 6;   // row-group 0..3
    __shared__ int se[2];
    __shared__ f32x4 pred[4][64];

    if (threadIdx.x == 0) {
        se[0] = lower_bound(bidx, N, g);
        se[1] = lower_bound(bidx, N, g + 1);
    }
    __syncthreads();
    const int start = se[0], end = se[1];
    const float gmax    = red[0];
    const float inv_den = 1.0f / red[1];

    const f32x4* zf = (const f32x4*)z;   // 80 f32x4 per row; use first 64

    f32x4 acc = (f32x4){0.f, 0.f, 0.f, 0.f};
    for (int i = start + rg; i < end; i += 4) {
        const float w = __expf(scores[i] - gmax);
        acc += w * zf[(size_t)i * 80 + lane];
    }
    pred[rg][lane] = acc;
    __syncthreads();

    if (rg == 0) {
        const f32x4 s = (pred[0][lane] + pred[1][lane]) +
                        (pred[2][lane] + pred[3][lane]);
        const int cnt = end - start;
        const float sc = inv_den / fmaxf((float)cnt, 1.0f);
        ((f32x4*)out)[(size_t)g * 64 + lane] = s * sc;
    }
}

// ---------------------------------------------------------------------------
extern "C" void kernel_launch(void* const* d_in, const int* in_sizes, int n_in,
                              void* d_out, int out_size, void* d_ws, size_t ws_size,
                              hipStream_t stream)
{
    const float* z    = (const float*)d_in[0];
    const int*   bidx = (const int*)  d_in[1];
    const float* W1   = (const float*)d_in[2];
    const float* b1   = (const float*)d_in[3];
    const float* W2   = (const float*)d_in[4];
    const float* b2   = (const float*)d_in[5];
    float*       out  = (float*)d_out;

    const int N  = in_sizes[0] / IN_DIM;       // 200000
    const int G  = out_size / POOL_DIM;        // 2000
    const int nb = (N + RPB - 1) / RPB;        // 1563 (<= 1600 padded)

    // workspace layout (16B-aligned slots)
    float*  scores = (float*)d_ws;             // N floats
    float*  bmax   = scores + 200000;          // pad region: nb <= 1600
    float*  bsum   = bmax + 1600;
    float*  red    = bsum + 1600;
    ushort* Wpk    = (ushort*)(red + 16);      // NKC*8*2*64*8 shorts = 160 KB

    pack_w1_kernel<<<(NKC * 8 * 2 * 64 + 255) / 256, 256, 0, stream>>>(W1, Wpk);
    attn_scores_mfma<<<nb, 256, 0, stream>>>(z, Wpk, b1, W2, b2,
                                             scores, bmax, bsum, N);
    softmax_reduce_kernel<<<1, 256, 0, stream>>>(bmax, bsum, red, nb);
    pool_kernel<<<G, 256, 0, stream>>>(z, bidx, scores, red, out, N);
}

// Round 10
// 112.397 us; speedup vs baseline: 1.0901x; 1.0391x over previous
//
#include <hip/hip_runtime.h>

#define IN_DIM   320
#define POOL_DIM 256
#define HID      128
#define RPB      128            // rows per block (4 waves x 32 rows)
#define NKC      10             // 320 / 32

typedef __attribute__((ext_vector_type(8))) short bf16x8;
typedef __attribute__((ext_vector_type(4))) float f32x4;

typedef __attribute__((address_space(1))) const unsigned int guint;
typedef __attribute__((address_space(3))) unsigned int luint;

__device__ __forceinline__ void gl_lds16(const void* g, void* l) {
    __builtin_amdgcn_global_load_lds((guint*)g, (luint*)l, 16, 0, 0);
}

__device__ __forceinline__ unsigned fbits(float f) {
    union { float f; unsigned u; } c; c.f = f; return c.u;
}
// pack bf16(trunc) of two f32 bit patterns: low16 = u0>>16, high16 = u1>>16
__device__ __forceinline__ unsigned pack2(unsigned u0, unsigned u1) {
    return __builtin_amdgcn_perm(u1, u0, 0x07060302u);
}

// split 8 f32 into hi(trunc-bf16) + lo(bf16 of residual); hi+lo ~ f32 exact
// to ~2^-16 relative.
__device__ __forceinline__ void split8(float4 a, float4 b, bf16x8& hi, bf16x8& lo) {
    float f[8] = { a.x, a.y, a.z, a.w, b.x, b.y, b.z, b.w };
    unsigned hu[8], lu[8];
#pragma unroll
    for (int i = 0; i < 8; ++i) {
        unsigned u = fbits(f[i]);
        hu[i] = u;
        float hif = __builtin_bit_cast(float, u & 0xffff0000u);
        lu[i] = fbits(f[i] - hif);
    }
    int4 hp, lp;
    hp.x = pack2(hu[0], hu[1]); hp.y = pack2(hu[2], hu[3]);
    hp.z = pack2(hu[4], hu[5]); hp.w = pack2(hu[6], hu[7]);
    lp.x = pack2(lu[0], lu[1]); lp.y = pack2(lu[2], lu[3]);
    lp.z = pack2(lu[4], lu[5]); lp.w = pack2(lu[6], lu[7]);
    hi = __builtin_bit_cast(bf16x8, hp);
    lo = __builtin_bit_cast(bf16x8, lp);
}

// ---------------------------------------------------------------------------
// One-time: pack W1 into MFMA B-fragment order, split hi/lo (frag-linear):
//   Wpk[((kc*16 + ht*2 + s)*64 + lane)*8 + j] =
//       split_s( W1[h = ht*16 + (lane&15)][k = kc*32 + (lane>>4)*8 + j] )
// Frag-linear => the 16KB per-kc chunk can be DMA'd to LDS verbatim.
// ---------------------------------------------------------------------------
__global__ __launch_bounds__(256) void pack_w1_kernel(
    const float* __restrict__ W1, ushort* __restrict__ Wpk)
{
    const int i = blockIdx.x * 256 + threadIdx.x;   // one bf16x8 group each
    if (i >= NKC * 8 * 2 * 64) return;
    const int kc   = i >> 10;
    const int r    = i & 1023;
    const int ht   = r >> 7;
    const int r2   = r & 127;
    const int s    = r2 >> 6;
    const int lane = r2 & 63;
    const int h    = ht * 16 + (lane & 15);
    const int k0   = kc * 32 + (lane >> 4) * 8;

    ushort v[8];
#pragma unroll
    for (int j = 0; j < 8; ++j) {
        const float f = W1[(size_t)h * IN_DIM + k0 + j];
        const unsigned u = fbits(f);
        if (s == 0) {
            v[j] = (ushort)(u >> 16);
        } else {
            const float hif = __builtin_bit_cast(float, u & 0xffff0000u);
            v[j] = (ushort)(fbits(f - hif) >> 16);
        }
    }
    ushort* dst = Wpk + (size_t)i * 8;
#pragma unroll
    for (int j = 0; j < 8; ++j) dst[j] = v[j];
}

// ---------------------------------------------------------------------------
// Kernel A: scores via split-bf16 MFMA.  BOTH streams (W frags and z chunk)
// double-buffered in LDS via global_load_lds, with COUNTED vmcnt waits
// (T4: never drain to 0 in the loop).  Prologue issues stages 0 and 1
// (8 vmem ops/thread each); iter kc waits vmcnt(8) -> stage kc landed while
// stage kc+1 stays in flight; after the read-release barrier, stage kc+2 is
// issued into the buffer just freed.  Epilogue constants (b1/W2/b2) are
// loaded & drained BEFORE the first stage so loop vmcnt counts stay exact.
// z LDS layout: slot = row*8 + (q ^ (row&7)), swizzle applied to the GLOBAL
// source quad (linear DMA dest); conflict-free b128 reads.
// mfma_f32_16x16x32_bf16: A row=l&15, k=(l>>4)*8+j; C/D col=l&15,
// row=(l>>4)*4+reg.  3-term split product (drop lo*lo ~ 2^-16 rel).
// ---------------------------------------------------------------------------
__global__ __launch_bounds__(256) void attn_scores_mfma(
    const float* __restrict__ z, const ushort* __restrict__ Wpk,
    const float* __restrict__ b1, const float* __restrict__ W2,
    const float* __restrict__ b2,
    float* __restrict__ scores, float* __restrict__ bmax,
    float* __restrict__ bsum, int N)
{
    __shared__ float4 wbuf[2][1024];   // 2 x 16 KB W-fragment buffers
    __shared__ float4 zbuf[2][1024];   // 2 x 16 KB z chunk buffers
    __shared__ float  sblk[RPB];

    const int tid  = threadIdx.x;
    const int wid  = tid >> 6;
    const int lane = tid & 63;
    const int lm   = lane & 15;
    const int lg   = lane >> 4;
    const int r0   = blockIdx.x * RPB;

    // per-thread z DMA source bases (4 slots, swizzled quad, row-clamped)
    const char* zsrc[4];
#pragma unroll
    for (int j = 0; j < 4; ++j) {
        const int s   = tid + j * 256;
        const int row = s >> 3;
        const int q   = (s & 7) ^ (row & 7);
        int gr = r0 + row; if (gr > N - 1) gr = N - 1;
        zsrc[j] = (const char*)z + (size_t)gr * (IN_DIM * 4) + q * 16;
    }

    #define STAGE_W(kc_, b_)                                                  \
        { const char* src = (const char*)Wpk + (size_t)(kc_) * 16384;         \
          char* dst = (char*)&wbuf[b_][0];                                    \
          _Pragma("unroll")                                                   \
          for (int j = 0; j < 4; ++j) {                                       \
              const int o = (tid + j * 256) * 16;                             \
              gl_lds16(src + o, dst + o);                                     \
          } }

    #define STAGE_Z(kc_, b_)                                                  \
        { char* dst = (char*)&zbuf[b_][0];                                    \
          _Pragma("unroll")                                                   \
          for (int j = 0; j < 4; ++j) {                                       \
              const int o = (tid + j * 256) * 16;                             \
              gl_lds16(zsrc[j] + (kc_) * 128, dst + o);                       \
          } }

    // ---- epilogue constants first, then drain, so the K-loop's vmcnt
    //      counts see ONLY the staging DMAs.
    float b1v[8], w2v[8];
#pragma unroll
    for (int ht = 0; ht < 8; ++ht) {
        b1v[ht] = b1[ht * 16 + lm];
        w2v[ht] = W2[ht * 16 + lm];
    }
    const float b2v = b2[0];
    asm volatile("s_waitcnt vmcnt(0)" ::: "memory");
    __builtin_amdgcn_sched_barrier(0);

    f32x4 acc[2][8];
#pragma unroll
    for (int rt = 0; rt < 2; ++rt)
#pragma unroll
        for (int ht = 0; ht < 8; ++ht) acc[rt][ht] = (f32x4){0.f, 0.f, 0.f, 0.f};

    // reader addresses (loop-invariant): two rows, two swizzled quads each
    const int lr0 = wid * 32 + lm;
    const int lr1 = lr0 + 16;
    const int i00 = lr0 * 8 + ((2 * lg)     ^ (lr0 & 7));
    const int i01 = lr0 * 8 + ((2 * lg + 1) ^ (lr0 & 7));
    const int i10 = lr1 * 8 + ((2 * lg)     ^ (lr1 & 7));
    const int i11 = lr1 * 8 + ((2 * lg + 1) ^ (lr1 & 7));

    // prologue: stages 0 and 1 in flight (8 ops/thread each)
    STAGE_Z(0, 0); STAGE_W(0, 0);
    STAGE_Z(1, 1); STAGE_W(1, 1);

#pragma unroll
    for (int kc = 0; kc < NKC; ++kc) {
        const int cb = kc & 1;           // constant after unroll

        // stage kc landed; stage kc+1 may remain in flight (8 newest ops)
        if (kc < NKC - 1) {
            asm volatile("s_waitcnt vmcnt(8)" ::: "memory");
        } else {
            asm volatile("s_waitcnt vmcnt(0)" ::: "memory");
        }
        __builtin_amdgcn_sched_barrier(0);
        __builtin_amdgcn_s_barrier();
        __builtin_amdgcn_sched_barrier(0);

        // z frags from LDS -> split8
        bf16x8 a0h, a0l, a1h, a1l;
        {
            const float4* zb = &zbuf[cb][0];
            const float4 x0 = zb[i00];
            const float4 x1 = zb[i01];
            const float4 y0 = zb[i10];
            const float4 y1 = zb[i11];
            split8(x0, x1, a0h, a0l);
            split8(y0, y1, a1h, a1l);
        }

        // W frags + MFMAs
        const char* wb_base = (const char*)&wbuf[cb][0] + lane * 16;
#pragma unroll
        for (int ht = 0; ht < 8; ++ht) {
            const bf16x8 bh = *(const bf16x8*)(wb_base + ht * 2048);
            const bf16x8 bl = *(const bf16x8*)(wb_base + ht * 2048 + 1024);
            acc[0][ht] = __builtin_amdgcn_mfma_f32_16x16x32_bf16(a0h, bh, acc[0][ht], 0, 0, 0);
            acc[0][ht] = __builtin_amdgcn_mfma_f32_16x16x32_bf16(a0l, bh, acc[0][ht], 0, 0, 0);
            acc[0][ht] = __builtin_amdgcn_mfma_f32_16x16x32_bf16(a0h, bl, acc[0][ht], 0, 0, 0);
            acc[1][ht] = __builtin_amdgcn_mfma_f32_16x16x32_bf16(a1h, bh, acc[1][ht], 0, 0, 0);
            acc[1][ht] = __builtin_amdgcn_mfma_f32_16x16x32_bf16(a1l, bh, acc[1][ht], 0, 0, 0);
            acc[1][ht] = __builtin_amdgcn_mfma_f32_16x16x32_bf16(a1h, bl, acc[1][ht], 0, 0, 0);
        }

        if (kc + 2 < NKC) {
            // release buf[cb]: all waves done reading it, then refill
            __builtin_amdgcn_sched_barrier(0);
            __builtin_amdgcn_s_barrier();
            __builtin_amdgcn_sched_barrier(0);
            STAGE_Z(kc + 2, cb);
            STAGE_W(kc + 2, cb);
        }
    }

    // ---- epilogue: relu + dot(W2) per lane-col, reduce over 16 cols
#pragma unroll
    for (int rt = 0; rt < 2; ++rt) {
#pragma unroll
        for (int reg = 0; reg < 4; ++reg) {
            float s = 0.f;
#pragma unroll
            for (int ht = 0; ht < 8; ++ht)
                s += fmaxf(acc[rt][ht][reg] + b1v[ht], 0.f) * w2v[ht];
            s += __shfl_xor(s, 1);
            s += __shfl_xor(s, 2);
            s += __shfl_xor(s, 4);
            s += __shfl_xor(s, 8);
            s += b2v;
            if (lm == 0) {
                const int rloc = wid * 32 + rt * 16 + lg * 4 + reg;
                const int grow = r0 + rloc;
                if (grow < N) {
                    scores[grow] = s;
                    sblk[rloc] = s;
                } else {
                    sblk[rloc] = -1e30f;
                }
            }
        }
    }
    __syncthreads();

    // ---- block (max, sum-exp): 128 scores folded into one wave
    if (tid < 64) {
        const float v0 = sblk[tid];
        const float v1 = sblk[tid + 64];
        float m = fmaxf(v0, v1);
#pragma unroll
        for (int d = 1; d < 64; d <<= 1) m = fmaxf(m, __shfl_xor(m, d, 64));
        float e = __expf(v0 - m) + __expf(v1 - m);
#pragma unroll
        for (int d = 1; d < 64; d <<= 1) e += __shfl_xor(e, d, 64);
        if (tid == 0) {
            bmax[blockIdx.x] = m;
            bsum[blockIdx.x] = e;
        }
    }
}

// ---------------------------------------------------------------------------
// Kernel B: combine per-block (max, sumexp) -> global max & softmax denom
// ---------------------------------------------------------------------------
__global__ __launch_bounds__(256) void softmax_reduce_kernel(
    const float* __restrict__ bmax, const float* __restrict__ bsum,
    float* __restrict__ red, int nb)
{
    __shared__ float sm[4];
    __shared__ float ss[4];
    const int tid = threadIdx.x;

    float m = -1e30f;
    for (int i = tid; i < nb; i += 256) m = fmaxf(m, bmax[i]);
#pragma unroll
    for (int d = 1; d < 64; d <<= 1) m = fmaxf(m, __shfl_xor(m, d, 64));
    if ((tid & 63) == 0) sm[tid >> 6] = m;
    __syncthreads();
    const float gmax = fmaxf(fmaxf(sm[0], sm[1]), fmaxf(sm[2], sm[3]));

    float s = 0.f;
    for (int i = tid; i < nb; i += 256) s += bsum[i] * __expf(bmax[i] - gmax);
#pragma unroll
    for (int d = 1; d < 64; d <<= 1) s += __shfl_xor(s, d, 64);
    if ((tid & 63) == 0) ss[tid >> 6] = s;
    __syncthreads();
    if (tid == 0) {
        red[0] = gmax;
        red[1] = ss[0] + ss[1] + ss[2] + ss[3];
    }
}

// ---------------------------------------------------------------------------
// Kernel E: per-graph weighted mean, float4-vectorized.
// Block = 256 threads = 4 row-groups x 64 float4-lanes (256 cols).
// ---------------------------------------------------------------------------
__device__ __forceinline__ int lower_bound(const int* __restrict__ a, int n, int key)
{
    int lo = 0, hi = n;
    while (lo < hi) {
        int mid = (lo + hi) >> 1;
        if (a[mid] < key) lo = mid + 1; else hi = mid;
    }
    return lo;
}

__global__ __launch_bounds__(256) void pool_kernel(
    const float* __restrict__ z, const int* __restrict__ bidx,
    const float* __restrict__ scores, const float* __restrict__ red,
    float* __restrict__ out, int N)
{
    const int g    = blockIdx.x;
    const int lane = threadIdx.x & 63;   // float4 column
    const int rg   = threadIdx.x >> 6;   // row-group 0..3
    __shared__ int se[2];
    __shared__ f32x4 pred[4][64];

    if (threadIdx.x == 0) {
        se[0] = lower_bound(bidx, N, g);
        se[1] = lower_bound(bidx, N, g + 1);
    }
    __syncthreads();
    const int start = se[0], end = se[1];
    const float gmax    = red[0];
    const float inv_den = 1.0f / red[1];

    const f32x4* zf = (const f32x4*)z;   // 80 f32x4 per row; use first 64

    f32x4 acc = (f32x4){0.f, 0.f, 0.f, 0.f};
    for (int i = start + rg; i < end; i += 4) {
        const float w = __expf(scores[i] - gmax);
        acc += w * zf[(size_t)i * 80 + lane];
    }
    pred[rg][lane] = acc;
    __syncthreads();

    if (rg == 0) {
        const f32x4 s = (pred[0][lane] + pred[1][lane]) +
                        (pred[2][lane] + pred[3][lane]);
        const int cnt = end - start;
        const float sc = inv_den / fmaxf((float)cnt, 1.0f);
        ((f32x4*)out)[(size_t)g * 64 + lane] = s * sc;
    }
}

// ---------------------------------------------------------------------------
extern "C" void kernel_launch(void* const* d_in, const int* in_sizes, int n_in,
                              void* d_out, int out_size, void* d_ws, size_t ws_size,
                              hipStream_t stream)
{
    const float* z    = (const float*)d_in[0];
    const int*   bidx = (const int*)  d_in[1];
    const float* W1   = (const float*)d_in[2];
    const float* b1   = (const float*)d_in[3];
    const float* W2   = (const float*)d_in[4];
    const float* b2   = (const float*)d_in[5];
    float*       out  = (float*)d_out;

    const int N  = in_sizes[0] / IN_DIM;       // 200000
    const int G  = out_size / POOL_DIM;        // 2000
    const int nb = (N + RPB - 1) / RPB;        // 1563 (<= 1600 padded)

    // workspace layout (16B-aligned slots)
    float*  scores = (float*)d_ws;             // N floats
    float*  bmax   = scores + 200000;          // pad region: nb <= 1600
    float*  bsum   = bmax + 1600;
    float*  red    = bsum + 1600;
    ushort* Wpk    = (ushort*)(red + 16);      // NKC*8*2*64*8 shorts = 160 KB

    pack_w1_kernel<<<(NKC * 8 * 2 * 64 + 255) / 256, 256, 0, stream>>>(W1, Wpk);
    attn_scores_mfma<<<nb, 256, 0, stream>>>(z, Wpk, b1, W2, b2,
                                             scores, bmax, bsum, N);
    softmax_reduce_kernel<<<1, 256, 0, stream>>>(bmax, bsum, red, nb);
    pool_kernel<<<G, 256, 0, stream>>>(z, bidx, scores, red, out, N);
}